// Round 5
// baseline (84.145 us; speedup 1.0000x reference)
//
#include <hip/hip_runtime.h>
#include <hip/hip_bf16.h>

typedef short bf16x8 __attribute__((ext_vector_type(8)));
typedef float f32x4  __attribute__((ext_vector_type(4)));

// RNE f32->bf16 (preload path)
__device__ inline ushort f2bf(float f) {
    union { float f; uint u; } v; v.f = f;
    uint r = (v.u + 0x7FFFu + ((v.u >> 16) & 1u)) >> 16;
    return (ushort)r;
}
// pair convert -> v_cvt_pk_bf16_f32
__device__ inline uint packbf(float a, float b) {
    float2 t; t.x = a; t.y = b;
    __hip_bfloat162 h = __float22bfloat162_rn(t);
    union { __hip_bfloat162 h; uint u; } cv; cv.h = h; return cv.u;
}

// ---- pre-kernel: pack x into bf16 rows of 8: [f0..f4, 1.0, 0, 0]; row N = zeros ----
__global__ __launch_bounds__(256) void pack_x_kernel(
    const float* __restrict__ x, uint4* __restrict__ xp, int N)
{
    int i = blockIdx.x * blockDim.x + threadIdx.x;
    if (i > N) return;
    uint4 o = {0u, 0u, 0u, 0u};
    if (i < N) {
        const float* r = x + (size_t)i * 5;
        o.x = packbf(r[0], r[1]);
        o.y = packbf(r[2], r[3]);
        o.z = packbf(r[4], 1.0f);   // slot 5 = 1.0 : bias enabler
    }
    xp[i] = o;
}

// Per wave: 32 edges (2 subtiles of 16). Block: 4 waves. No LDS, no barriers.
// EF k-layout: k=0..4 src feats, k=5 = 1.0 (b1 row), k=8..12 tgt feats, else 0.
// Layer2 consumes layer1's C-frag via formal-K permutation
//   sigma(t,g,d): hid1 = 16*(2t+(d>>2)) + 4g + (d&3); slot hid1==50 := b2 (h1[50]==1).
__global__ __launch_bounds__(256, 4) void edge_mlp_mfma3(
    const uint4* __restrict__ xp,
    const int* __restrict__ ei,
    const float* __restrict__ W1, const float* __restrict__ b1,
    const float* __restrict__ W2, const float* __restrict__ b2,
    const float* __restrict__ W3, const float* __restrict__ b3,
    float* __restrict__ out, int E, int N, int num_tiles)
{
    const int tid  = threadIdx.x;
    const int w    = tid >> 6;
    const int lane = tid & 63;
    const int c    = lane & 15;   // edge-in-subtile
    const int g    = lane >> 4;   // k-group / hid-row group

    // ---- W1^T A-frags: row j=16mt+c, k=8g+d over EF k-layout (b1 at k=5) ----
    bf16x8 w1f[4];
    #pragma unroll
    for (int mt = 0; mt < 4; ++mt) {
        #pragma unroll
        for (int d = 0; d < 8; ++d) {
            int k = 8 * g + d;
            int j = 16 * mt + c;
            float v = 0.f;
            if (j < 50) {
                if (k < 5)                 v = W1[k * 50 + j];
                else if (k == 5)           v = b1[j];
                else if (k >= 8 && k < 13) v = W1[(k - 3) * 50 + j];
            } else if (j == 50 && k == 5)  v = 1.0f;   // h1[50] := 1 (b2 enabler)
            w1f[mt][d] = (short)f2bf(v);
        }
    }
    // ---- W2^T A-frags with sigma; hid1==50 row := b2 ----
    bf16x8 w2f[2][4];
    #pragma unroll
    for (int t = 0; t < 2; ++t) {
        #pragma unroll
        for (int mt = 0; mt < 4; ++mt) {
            #pragma unroll
            for (int d = 0; d < 8; ++d) {
                int hid1 = 16 * (2 * t + (d >> 2)) + 4 * g + (d & 3);
                int j    = 16 * mt + c;
                float v = 0.f;
                if (j < 50) {
                    if (hid1 < 50)       v = W2[hid1 * 50 + j];
                    else if (hid1 == 50) v = b2[j];
                }
                w2f[t][mt][d] = (short)f2bf(v);
            }
        }
    }
    // W3 per-lane slice, hid = 16mt+4g+r
    float w3c[4][4];
    #pragma unroll
    for (int mt = 0; mt < 4; ++mt)
        #pragma unroll
        for (int r = 0; r < 4; ++r) {
            int h = 16 * mt + 4 * g + r;
            w3c[mt][r] = (h < 50) ? W3[h] : 0.f;
        }
    const float b3s = b3[0];

    for (int bt = blockIdx.x; bt < num_tiles; bt += gridDim.x) {
        const int e0 = bt * 128 + w * 32;

        // ---- direct EF fragment gather: lane (c,g<2) = x_pad[ei[g*E + e]] ----
        bf16x8 aEF[2];
        #pragma unroll
        for (int ms = 0; ms < 2; ++ms) {
            int e   = e0 + ms * 16 + c;
            int idx = N;                               // zero row for g>=2
            if (g < 2) {
                int ee = (e < E) ? e : 0;
                idx = ei[(size_t)g * (size_t)E + (size_t)ee];
            }
            union { uint4 q; bf16x8 v; } u;
            u.q = xp[idx];
            aEF[ms] = u.v;
        }

        #pragma unroll
        for (int ms = 0; ms < 2; ++ms) {
            // ---- layer 1 (+b1): h1^T = W1ext^T @ EF^T ----
            f32x4 hT[4];
            #pragma unroll
            for (int mt = 0; mt < 4; ++mt) {
                f32x4 z = {0.f, 0.f, 0.f, 0.f};
                hT[mt] = __builtin_amdgcn_mfma_f32_16x16x32_bf16(w1f[mt], aEF[ms], z, 0, 0, 0);
            }
            // ---- relu + pack: C-frag becomes layer-2 B-frags (sigma baked in W2) ----
            uint pk[4][2];
            #pragma unroll
            for (int mt = 0; mt < 4; ++mt) {
                float v0 = fmaxf(hT[mt][0], 0.f);
                float v1 = fmaxf(hT[mt][1], 0.f);
                float v2 = fmaxf(hT[mt][2], 0.f);
                float v3 = fmaxf(hT[mt][3], 0.f);
                pk[mt][0] = packbf(v0, v1);
                pk[mt][1] = packbf(v2, v3);
            }
            union { uint u[4]; bf16x8 v; } uu;
            uu.u[0] = pk[0][0]; uu.u[1] = pk[0][1];
            uu.u[2] = pk[1][0]; uu.u[3] = pk[1][1];
            bf16x8 bB0 = uu.v;
            uu.u[0] = pk[2][0]; uu.u[1] = pk[2][1];
            uu.u[2] = pk[3][0]; uu.u[3] = pk[3][1];
            bf16x8 bB1 = uu.v;

            // ---- layer 2 (+b2): h2^T = W2ext^T @ h1^T ----
            f32x4 h2T[4];
            #pragma unroll
            for (int mt = 0; mt < 4; ++mt) {
                f32x4 z = {0.f, 0.f, 0.f, 0.f};
                h2T[mt] = __builtin_amdgcn_mfma_f32_16x16x32_bf16(w2f[0][mt], bB0, z, 0, 0, 0);
                h2T[mt] = __builtin_amdgcn_mfma_f32_16x16x32_bf16(w2f[1][mt], bB1, h2T[mt], 0, 0, 0);
            }

            // ---- layer 3: relu + per-lane dot, reduce over g-groups ----
            float p = 0.f;
            #pragma unroll
            for (int mt = 0; mt < 4; ++mt) {
                #pragma unroll
                for (int r = 0; r < 4; ++r) {
                    float t = fmaxf(h2T[mt][r], 0.f);
                    p = fmaf(t, w3c[mt][r], p);
                }
            }
            p += __shfl_xor(p, 16);
            p += __shfl_xor(p, 32);

            if (g == 0) {
                int e = e0 + ms * 16 + c;
                if (e < E) {
                    float zz = p + b3s;
                    out[e] = 1.f / (1.f + __expf(-zz));
                }
            }
        }
    }
}

extern "C" void kernel_launch(void* const* d_in, const int* in_sizes, int n_in,
                              void* d_out, int out_size, void* d_ws, size_t ws_size,
                              hipStream_t stream) {
    const float* x  = (const float*)d_in[0];
    const int*   ei = (const int*)d_in[1];
    const float* W1 = (const float*)d_in[2];
    const float* b1 = (const float*)d_in[3];
    const float* W2 = (const float*)d_in[4];
    const float* b2 = (const float*)d_in[5];
    const float* W3 = (const float*)d_in[6];
    const float* b3 = (const float*)d_in[7];
    float* out = (float*)d_out;

    int E = in_sizes[1] / 2;      // edge_index is [2, E]
    int N = in_sizes[0] / 5;      // nodes

    uint4* xp = (uint4*)d_ws;     // (N+1) * 16 bytes
    pack_x_kernel<<<(N + 1 + 255) / 256, 256, 0, stream>>>(x, xp, N);

    int num_tiles = (E + 127) / 128;
    int grid = num_tiles < 2048 ? num_tiles : 2048;
    edge_mlp_mfma3<<<grid, 256, 0, stream>>>(xp, ei, W1, b1, W2, b2, W3, b3,
                                             out, E, N, num_tiles);
}

// Round 6
// 79.975 us; speedup vs baseline: 1.0521x; 1.0521x over previous
//
#include <hip/hip_runtime.h>
#include <hip/hip_bf16.h>

typedef short bf16x8 __attribute__((ext_vector_type(8)));
typedef float f32x4  __attribute__((ext_vector_type(4)));

// RNE f32->bf16 (pre-kernels only)
__device__ inline ushort f2bf(float f) {
    union { float f; uint u; } v; v.f = f;
    uint r = (v.u + 0x7FFFu + ((v.u >> 16) & 1u)) >> 16;
    return (ushort)r;
}
// pair convert -> v_cvt_pk_bf16_f32
__device__ inline uint packbf(float a, float b) {
    float2 t; t.x = a; t.y = b;
    __hip_bfloat162 h = __float22bfloat162_rn(t);
    union { __hip_bfloat162 h; uint u; } cv; cv.h = h; return cv.u;
}

// ---- pre-kernel A: pack x into bf16 rows of 8: [f0..f4, 1.0, 0, 0]; row N = zeros ----
__global__ __launch_bounds__(256) void pack_x_kernel(
    const float* __restrict__ x, uint4* __restrict__ xp, int N)
{
    int i = blockIdx.x * blockDim.x + threadIdx.x;
    if (i > N) return;
    uint4 o = {0u, 0u, 0u, 0u};
    if (i < N) {
        const float* r = x + (size_t)i * 5;
        o.x = packbf(r[0], r[1]);
        o.y = packbf(r[2], r[3]);
        o.z = packbf(r[4], 1.0f);   // slot 5 = 1.0 : bias enabler
    }
    xp[i] = o;
}

// ---- pre-kernel B: bake per-lane weight fragments (16 chunks x 64 lanes x 16B) ----
// chunk 0..3   : W1^T A-frags  (EF k-layout, b1 at k=5, h1[50]:=1 enabler)
// chunk 4..11  : W2^T A-frags with formal-K permutation sigma; hid1==50 := b2
// chunk 12..15 : W3 per-lane f32x4 slices (hid = 16mt+4g+r)
__global__ __launch_bounds__(64) void pack_w_kernel(
    const float* __restrict__ W1, const float* __restrict__ b1,
    const float* __restrict__ W2, const float* __restrict__ b2,
    const float* __restrict__ W3, uint4* __restrict__ tab)
{
    const int lane = threadIdx.x;       // one wave
    const int c = lane & 15;
    const int g = lane >> 4;

    union { ushort s[8]; uint4 q; } u;
    #pragma unroll
    for (int mt = 0; mt < 4; ++mt) {
        #pragma unroll
        for (int d = 0; d < 8; ++d) {
            int k = 8 * g + d;
            int j = 16 * mt + c;
            float v = 0.f;
            if (j < 50) {
                if (k < 5)                 v = W1[k * 50 + j];
                else if (k == 5)           v = b1[j];
                else if (k >= 8 && k < 13) v = W1[(k - 3) * 50 + j];
            } else if (j == 50 && k == 5)  v = 1.0f;
            u.s[d] = f2bf(v);
        }
        tab[mt * 64 + lane] = u.q;
    }
    #pragma unroll
    for (int t = 0; t < 2; ++t) {
        #pragma unroll
        for (int mt = 0; mt < 4; ++mt) {
            #pragma unroll
            for (int d = 0; d < 8; ++d) {
                int hid1 = 16 * (2 * t + (d >> 2)) + 4 * g + (d & 3);
                int j    = 16 * mt + c;
                float v = 0.f;
                if (j < 50) {
                    if (hid1 < 50)       v = W2[hid1 * 50 + j];
                    else if (hid1 == 50) v = b2[j];
                }
                u.s[d] = f2bf(v);
            }
            tab[(4 + t * 4 + mt) * 64 + lane] = u.q;
        }
    }
    union { float f[4]; uint4 q; } wq;
    #pragma unroll
    for (int mt = 0; mt < 4; ++mt) {
        #pragma unroll
        for (int r = 0; r < 4; ++r) {
            int h = 16 * mt + 4 * g + r;
            wq.f[r] = (h < 50) ? W3[h] : 0.f;
        }
        tab[(12 + mt) * 64 + lane] = wq.q;
    }
}

// ---- main: per wave 32 edges (2 subtiles of 16); weights from LDS frag table ----
__global__ __launch_bounds__(256, 4) void edge_mlp_mfma4(
    const uint4* __restrict__ xp,
    const uint4* __restrict__ wtab,
    const int* __restrict__ ei,
    const float* __restrict__ b3,
    float* __restrict__ out, int E, int N, int num_tiles)
{
    __shared__ uint4 lds_frag[1024];    // 16 KB

    const int tid = threadIdx.x;
    #pragma unroll
    for (int i = 0; i < 4; ++i) lds_frag[tid + 256 * i] = wtab[tid + 256 * i];
    __syncthreads();

    const int w    = tid >> 6;
    const int lane = tid & 63;
    const int c    = lane & 15;
    const int g    = lane >> 4;

    // loop-invariant fragment loads (1 ds_read_b128 each; cheap even if sunk)
    bf16x8 w1f[4];
    #pragma unroll
    for (int mt = 0; mt < 4; ++mt)
        w1f[mt] = *(const bf16x8*)&lds_frag[mt * 64 + lane];
    bf16x8 w2f[2][4];
    #pragma unroll
    for (int t = 0; t < 2; ++t)
        #pragma unroll
        for (int mt = 0; mt < 4; ++mt)
            w2f[t][mt] = *(const bf16x8*)&lds_frag[(4 + t * 4 + mt) * 64 + lane];
    f32x4 w3c[4];
    #pragma unroll
    for (int mt = 0; mt < 4; ++mt)
        w3c[mt] = *(const f32x4*)&lds_frag[(12 + mt) * 64 + lane];
    const float b3s = b3[0];

    for (int bt = blockIdx.x; bt < num_tiles; bt += gridDim.x) {
        const int e0 = bt * 128 + w * 32;

        // direct EF fragment gather: lane (c, g<2) = x_pad[ei[g*E + e]]
        bf16x8 aEF[2];
        #pragma unroll
        for (int ms = 0; ms < 2; ++ms) {
            int e   = e0 + ms * 16 + c;
            int idx = N;                               // zero row for g>=2
            if (g < 2) {
                int ee = (e < E) ? e : 0;
                idx = ei[(size_t)g * (size_t)E + (size_t)ee];
            }
            union { uint4 q; bf16x8 v; } u;
            u.q = xp[idx];
            aEF[ms] = u.v;
        }

        #pragma unroll
        for (int ms = 0; ms < 2; ++ms) {
            // layer 1 (+b1 folded): h1^T = W1ext^T @ EF^T
            f32x4 hT[4];
            #pragma unroll
            for (int mt = 0; mt < 4; ++mt) {
                f32x4 z = {0.f, 0.f, 0.f, 0.f};
                hT[mt] = __builtin_amdgcn_mfma_f32_16x16x32_bf16(w1f[mt], aEF[ms], z, 0, 0, 0);
            }
            // relu + pack: C-frag becomes layer-2 B-frags (sigma baked into W2 frags)
            uint pk[4][2];
            #pragma unroll
            for (int mt = 0; mt < 4; ++mt) {
                float v0 = fmaxf(hT[mt][0], 0.f);
                float v1 = fmaxf(hT[mt][1], 0.f);
                float v2 = fmaxf(hT[mt][2], 0.f);
                float v3 = fmaxf(hT[mt][3], 0.f);
                pk[mt][0] = packbf(v0, v1);
                pk[mt][1] = packbf(v2, v3);
            }
            union { uint u[4]; bf16x8 v; } uu;
            uu.u[0] = pk[0][0]; uu.u[1] = pk[0][1];
            uu.u[2] = pk[1][0]; uu.u[3] = pk[1][1];
            bf16x8 bB0 = uu.v;
            uu.u[0] = pk[2][0]; uu.u[1] = pk[2][1];
            uu.u[2] = pk[3][0]; uu.u[3] = pk[3][1];
            bf16x8 bB1 = uu.v;

            // layer 2 (+b2 folded): h2^T = W2ext^T @ h1^T
            f32x4 h2T[4];
            #pragma unroll
            for (int mt = 0; mt < 4; ++mt) {
                f32x4 z = {0.f, 0.f, 0.f, 0.f};
                h2T[mt] = __builtin_amdgcn_mfma_f32_16x16x32_bf16(w2f[0][mt], bB0, z, 0, 0, 0);
                h2T[mt] = __builtin_amdgcn_mfma_f32_16x16x32_bf16(w2f[1][mt], bB1, h2T[mt], 0, 0, 0);
            }

            // layer 3: relu + per-lane dot, reduce over g-groups
            float p = 0.f;
            #pragma unroll
            for (int mt = 0; mt < 4; ++mt) {
                #pragma unroll
                for (int r = 0; r < 4; ++r) {
                    float t = fmaxf(h2T[mt][r], 0.f);
                    p = fmaf(t, w3c[mt][r], p);
                }
            }
            p += __shfl_xor(p, 16);
            p += __shfl_xor(p, 32);

            if (g == 0) {
                int e = e0 + ms * 16 + c;
                if (e < E) {
                    float zz = p + b3s;
                    out[e] = 1.f / (1.f + __expf(-zz));
                }
            }
        }
    }
}

extern "C" void kernel_launch(void* const* d_in, const int* in_sizes, int n_in,
                              void* d_out, int out_size, void* d_ws, size_t ws_size,
                              hipStream_t stream) {
    const float* x  = (const float*)d_in[0];
    const int*   ei = (const int*)d_in[1];
    const float* W1 = (const float*)d_in[2];
    const float* b1 = (const float*)d_in[3];
    const float* W2 = (const float*)d_in[4];
    const float* b2 = (const float*)d_in[5];
    const float* W3 = (const float*)d_in[6];
    const float* b3 = (const float*)d_in[7];
    float* out = (float*)d_out;

    int E = in_sizes[1] / 2;      // edge_index is [2, E]
    int N = in_sizes[0] / 5;      // nodes

    uint4* wtab = (uint4*)d_ws;                    // 16 KB fragment table
    uint4* xp   = (uint4*)((char*)d_ws + 16384);   // (N+1) * 16 B packed x

    pack_w_kernel<<<1, 64, 0, stream>>>(W1, b1, W2, b2, W3, wtab);
    pack_x_kernel<<<(N + 1 + 255) / 256, 256, 0, stream>>>(x, xp, N);

    int num_tiles = (E + 127) / 128;
    int grid = num_tiles < 2048 ? num_tiles : 2048;
    edge_mlp_mfma4<<<grid, 256, 0, stream>>>(xp, wtab, ei, b3, out, E, N, num_tiles);
}